// Round 1
// baseline (794.714 us; speedup 1.0000x reference)
//
#include <hip/hip_runtime.h>
#include <hip/hip_bf16.h>
#include <stdint.h>

// ---------------------------------------------------------------------------
// Mlp_cnn_shift: B=2 T=8 H=56 W=56 C=512 HID=1024, N = 50176 tokens
// Pipeline:
//  xb   = bf16(x)                                  [N,512]
//  xh   = gelu(xb @ fc_w + fc_b)                   [N,1024]  bf16
//  xs   = shift_fwd(xh)   (group=114)              [N,1024]  bf16 (in d_out)
//  hpre = gelu(xs @ fc1_w + fc1_b)                 [N,512]   bf16
//  w    = gelu(xh @ fc2_w + fc2_b)                 [N,512]   bf16 (in d_out)
//  s0   = sum over (t,oh,ow) of shift_inv(hpre);  s1 = sum of w     (masked sums)
//  a0,a1 = softmax pair of tiny MLP(mean)          [2,512]   fp32 (exact)
//  hw   = shift_inv(hpre)*a0 + w*a1                [N,512]   bf16
//  out  = hw @ proj_w + proj_b                     [N,512]   fp32 -> d_out
// ---------------------------------------------------------------------------

typedef __attribute__((ext_vector_type(8))) short short8;
typedef __attribute__((ext_vector_type(4))) float floatx4;
typedef unsigned int uint;
typedef unsigned short ushort;

#define NTOK   50176
#define BT_CNT 16      // B*T
#define HWIMG  3136    // 56*56

__device__ __forceinline__ float gelu_f(float v) {
    return 0.5f * v * (1.0f + erff(v * 0.70710678118654752440f));
}

// shifts: g in 0..8 -> (1-g/3, 1-g%3) matches SHIFTS table
__device__ __forceinline__ int shift_h(int g) { return 1 - g / 3; }
__device__ __forceinline__ int shift_w(int g) { return 1 - g % 3; }

// ---- async global->LDS, 16B per lane ---------------------------------------
typedef const __attribute__((address_space(1))) uint* gas_ptr;
typedef __attribute__((address_space(3))) uint* las_ptr;

__device__ __forceinline__ void async_copy16(const void* g, void* l) {
    gas_ptr gp = (gas_ptr)(uintptr_t)g;
    las_ptr lp = (las_ptr)(uint32_t)(uintptr_t)l;
    __builtin_amdgcn_global_load_lds(gp, lp, 16, 0, 0);
}

// ---- GEMM: C[M,N] = act(A[M,K] @ Bt[N,K]^T + bias), m97-style --------------
// BM=BN=128, BK=32, 256 threads = 4 waves (2x2), each wave 64x64 (4x4 mfma 16x16x32)
template <int GELU_F, int OUT_BF16>
__global__ __launch_bounds__(256) void gemm_bt(
    const __hip_bfloat16* __restrict__ A,
    const __hip_bfloat16* __restrict__ Bt,
    const float* __restrict__ bias,
    void* __restrict__ Cout, int N, int K)
{
    __shared__ __hip_bfloat16 As[128 * 32];
    __shared__ __hip_bfloat16 Bs[128 * 32];

    const int t    = threadIdx.x;
    const int bn   = blockIdx.x;
    const int bm   = blockIdx.y;
    const int lane = t & 63;
    const int wave = t >> 6;
    const int wm   = wave >> 1;   // 0..1
    const int wn   = wave & 1;    // 0..1

    // staging: 512 chunks of 16B per tile; thread t does chunks t and t+256
    // chunk c -> row c>>2, kchunk c&3 ; LDS byte offset = c*16 (row-major [128][32])
    const __hip_bfloat16* ga0 = A  + (size_t)(bm * 128 + (t >> 2)) * K + (t & 3) * 8;
    const __hip_bfloat16* ga1 = ga0 + (size_t)64 * K;
    const __hip_bfloat16* gb0 = Bt + (size_t)(bn * 128 + (t >> 2)) * K + (t & 3) * 8;
    const __hip_bfloat16* gb1 = gb0 + (size_t)64 * K;
    __hip_bfloat16* la0 = &As[t * 8];
    __hip_bfloat16* la1 = &As[t * 8 + 2048];
    __hip_bfloat16* lb0 = &Bs[t * 8];
    __hip_bfloat16* lb1 = &Bs[t * 8 + 2048];

    floatx4 acc[4][4] = {};

    const int kq = (lane >> 4) * 8;   // k-chunk within BK for this lane quad
    const int ml = lane & 15;

    for (int k0 = 0; k0 < K; k0 += 32) {
        async_copy16(ga0, la0);
        async_copy16(ga1, la1);
        async_copy16(gb0, lb0);
        async_copy16(gb1, lb1);
        ga0 += 32; ga1 += 32; gb0 += 32; gb1 += 32;
        asm volatile("s_waitcnt vmcnt(0)" ::: "memory");
        __syncthreads();

        short8 af[4], bf[4];
#pragma unroll
        for (int i = 0; i < 4; i++) {
            af[i] = *(const short8*)&As[(wm * 64 + i * 16 + ml) * 32 + kq];
            bf[i] = *(const short8*)&Bs[(wn * 64 + i * 16 + ml) * 32 + kq];
        }
#pragma unroll
        for (int mi = 0; mi < 4; mi++)
#pragma unroll
            for (int ni = 0; ni < 4; ni++)
                acc[mi][ni] = __builtin_amdgcn_mfma_f32_16x16x32_bf16(
                    af[mi], bf[ni], acc[mi][ni], 0, 0, 0);
        __syncthreads();
    }

    // epilogue: C/D layout col = lane&15, row = (lane>>4)*4 + reg  (m89-verified)
    const int rq = (lane >> 4) * 4;
#pragma unroll
    for (int mi = 0; mi < 4; mi++) {
#pragma unroll
        for (int ni = 0; ni < 4; ni++) {
            const int col = bn * 128 + wn * 64 + ni * 16 + ml;
            const float bv = bias[col];
#pragma unroll
            for (int r = 0; r < 4; r++) {
                const int row = bm * 128 + wm * 64 + mi * 16 + rq + r;
                float v = acc[mi][ni][r] + bv;
                if (GELU_F) v = gelu_f(v);
                if (OUT_BF16)
                    ((__hip_bfloat16*)Cout)[(size_t)row * N + col] = __float2bfloat16(v);
                else
                    ((float*)Cout)[(size_t)row * N + col] = v;
            }
        }
    }
}

// ---- prep: x fp32 -> bf16 ---------------------------------------------------
__global__ __launch_bounds__(256) void cvt_x(const float4* __restrict__ x,
                                             __hip_bfloat16* __restrict__ xb, int n4)
{
    int i = blockIdx.x * 256 + threadIdx.x;
    if (i >= n4) return;
    float4 v = x[i];
    __hip_bfloat16 b0 = __float2bfloat16(v.x);
    __hip_bfloat16 b1 = __float2bfloat16(v.y);
    __hip_bfloat16 b2 = __float2bfloat16(v.z);
    __hip_bfloat16 b3 = __float2bfloat16(v.w);
    uint2 o;
    o.x = (uint)*(ushort*)&b0 | ((uint)*(ushort*)&b1 << 16);
    o.y = (uint)*(ushort*)&b2 | ((uint)*(ushort*)&b3 << 16);
    *(uint2*)&xb[(size_t)i * 4] = o;
}

// ---- prep: transpose + convert the 4 weight matrices to bf16 Bt layout -----
__global__ __launch_bounds__(256) void prep_w(
    const float* __restrict__ fcw,  const float* __restrict__ fc1w,
    const float* __restrict__ fc2w, const float* __restrict__ projw,
    __hip_bfloat16* __restrict__ fcwT, __hip_bfloat16* __restrict__ fc1T,
    __hip_bfloat16* __restrict__ fc2T, __hip_bfloat16* __restrict__ projT)
{
    int i = blockIdx.x * 256 + threadIdx.x;
    if (i < 524288) {                       // fc_w [512,1024] -> [1024,512]
        int n = i >> 9, k = i & 511;
        fcwT[i] = __float2bfloat16(fcw[k * 1024 + n]);
    } else if (i < 1048576) {               // fc1_w [1024,512] -> [512,1024]
        int j = i - 524288;
        int n = j >> 10, k = j & 1023;
        fc1T[j] = __float2bfloat16(fc1w[k * 512 + n]);
    } else if (i < 1572864) {               // fc2_w [1024,512] -> [512,1024]
        int j = i - 1048576;
        int n = j >> 10, k = j & 1023;
        fc2T[j] = __float2bfloat16(fc2w[k * 512 + n]);
    } else if (i < 1835008) {               // proj_w [512,512] -> [512,512]
        int j = i - 1572864;
        int n = j >> 9, k = j & 511;
        projT[j] = __float2bfloat16(projw[k * 512 + n]);
    }
}

// ---- forward shift on xh (C=1024, group=114): xs[oh,ow,c] = xh[oh-sh,ow-sw,c] or 0
__global__ __launch_bounds__(256) void shift_fwd(const __hip_bfloat16* __restrict__ xh,
                                                 __hip_bfloat16* __restrict__ xs)
{
    const int blk = blockIdx.x;          // bt*56 + oh
    const int oh = blk % 56, bt = blk / 56;
    for (int idx = threadIdx.x; idx < 56 * 512; idx += 256) {
        const int ow = idx >> 9;
        const int c = (idx & 511) * 2;   // even pairs never straddle group (114 even)
        const int g = c / 114;
        const int ih = oh - shift_h(g), iw = ow - shift_w(g);
        uint v = 0;
        if ((unsigned)ih < 56u && (unsigned)iw < 56u)
            v = *(const uint*)&xh[((size_t)(bt * HWIMG + ih * 56 + iw)) * 1024 + c];
        *(uint*)&xs[((size_t)(bt * HWIMG + oh * 56 + ow)) * 1024 + c] = v;
    }
}

// ---- masked sums: s0[b,c] = sum shift_inv(hpre), s1[b,c] = sum w -----------
__global__ __launch_bounds__(256) void reduce_hw(const __hip_bfloat16* __restrict__ hpre,
                                                 const __hip_bfloat16* __restrict__ wbuf,
                                                 float* __restrict__ s0, float* __restrict__ s1)
{
    const int blk = blockIdx.x;          // bt*56 + ih
    const int ih = blk % 56, bt = blk / 56, b = bt >> 3;
    const int c = threadIdx.x * 2;
    const int g0 = c / 57, g1 = (c + 1) / 57;
    // row validity of this input row under the inverse shift
    const int sh0 = shift_h(g0), sh1 = shift_h(g1);
    const bool r0 = (sh0 == 1) ? (ih >= 1) : ((sh0 == -1) ? (ih <= 54) : true);
    const bool r1 = (sh1 == 1) ? (ih >= 1) : ((sh1 == -1) ? (ih <= 54) : true);
    const int sw0 = shift_w(g0), sw1 = shift_w(g1);
    const int lo0 = (sw0 == 1) ? 1 : 0, hi0 = (sw0 == -1) ? 54 : 55;
    const int lo1 = (sw1 == 1) ? 1 : 0, hi1 = (sw1 == -1) ? 54 : 55;

    float h0 = 0.f, h1 = 0.f, w0 = 0.f, w1 = 0.f;
    const size_t base = ((size_t)(bt * HWIMG + ih * 56)) * 512 + c;
    for (int iw = 0; iw < 56; iw++) {
        const uint hv = *(const uint*)&hpre[base + (size_t)iw * 512];
        const uint wv = *(const uint*)&wbuf[base + (size_t)iw * 512];
        const float fh0 = __uint_as_float(hv << 16);
        const float fh1 = __uint_as_float(hv & 0xffff0000u);
        const float fw0 = __uint_as_float(wv << 16);
        const float fw1 = __uint_as_float(wv & 0xffff0000u);
        if (r0 && iw >= lo0 && iw <= hi0) h0 += fh0;
        if (r1 && iw >= lo1 && iw <= hi1) h1 += fh1;
        w0 += fw0; w1 += fw1;
    }
    atomicAdd(&s0[b * 512 + c], h0);
    atomicAdd(&s0[b * 512 + c + 1], h1);
    atomicAdd(&s1[b * 512 + c], w0);
    atomicAdd(&s1[b * 512 + c + 1], w1);
}

// ---- tiny squeeze-excite MLP + pairwise softmax, fp32 exact ----------------
__global__ __launch_bounds__(256) void tiny_mlp(
    const float* __restrict__ s0, const float* __restrict__ s1,
    const float* __restrict__ rw1_w, const float* __restrict__ rw1_b,
    const float* __restrict__ rw2_w, const float* __restrict__ rw2_b,
    float* __restrict__ a0, float* __restrict__ a1)
{
    __shared__ float mean[1024];   // [2][512]
    __shared__ float z[256];       // [2][128]
    __shared__ float av[2048];     // [2][1024]
    const int t = threadIdx.x;
    for (int i = t; i < 1024; i += 256)
        mean[i] = (s0[i] + s1[i]) * (1.0f / 25088.0f);
    __syncthreads();
    {
        const int b = t >> 7, j = t & 127;
        float acc = rw1_b[j];
        for (int cc = 0; cc < 512; cc++)
            acc += mean[b * 512 + cc] * rw1_w[cc * 128 + j];
        z[t] = gelu_f(acc);
    }
    __syncthreads();
    for (int i = t; i < 2048; i += 256) {
        const int b = i >> 10, o = i & 1023;
        float acc = rw2_b[o];
        for (int j = 0; j < 128; j++)
            acc += z[b * 128 + j] * rw2_w[j * 1024 + o];
        av[i] = acc;
    }
    __syncthreads();
    for (int i = t; i < 1024; i += 256) {
        const int b = i >> 9, cc = i & 511;
        const float x0 = av[b * 1024 + 2 * cc];
        const float x1 = av[b * 1024 + 2 * cc + 1];
        const float m = fmaxf(x0, x1);
        const float e0 = expf(x0 - m), e1 = expf(x1 - m);
        const float inv = 1.0f / (e0 + e1);
        a0[i] = e0 * inv;
        a1[i] = e1 * inv;
    }
}

// ---- hw = shift_inv(hpre)*a0 + w*a1 (C=512, group=57) ----------------------
__global__ __launch_bounds__(256) void combine(const __hip_bfloat16* __restrict__ hpre,
                                               const __hip_bfloat16* __restrict__ wbuf,
                                               const float* __restrict__ a0,
                                               const float* __restrict__ a1,
                                               __hip_bfloat16* __restrict__ hw)
{
    const int blk = blockIdx.x;          // bt*56 + oh
    const int oh = blk % 56, bt = blk / 56, b = bt >> 3;
    for (int idx = threadIdx.x; idx < 56 * 512; idx += 256) {
        const int ow = idx >> 9, c = idx & 511;
        const int g = c / 57;
        const int ih = oh + shift_h(g), iw = ow + shift_w(g);
        float hv = 0.f;
        if ((unsigned)ih < 56u && (unsigned)iw < 56u)
            hv = (float)hpre[((size_t)(bt * HWIMG + ih * 56 + iw)) * 512 + c];
        const float wv = (float)wbuf[((size_t)(bt * HWIMG + oh * 56 + ow)) * 512 + c];
        hw[((size_t)(bt * HWIMG + oh * 56 + ow)) * 512 + c] =
            __float2bfloat16(hv * a0[b * 512 + c] + wv * a1[b * 512 + c]);
    }
}

// ---------------------------------------------------------------------------
extern "C" void kernel_launch(void* const* d_in, const int* in_sizes, int n_in,
                              void* d_out, int out_size, void* d_ws, size_t ws_size,
                              hipStream_t stream)
{
    const float* x      = (const float*)d_in[0];
    const float* fc_w   = (const float*)d_in[1];
    const float* fc_b   = (const float*)d_in[2];
    const float* fc1_w  = (const float*)d_in[3];
    const float* fc1_b  = (const float*)d_in[4];
    const float* fc2_w  = (const float*)d_in[5];
    const float* fc2_b  = (const float*)d_in[6];
    const float* rw1_w  = (const float*)d_in[7];
    const float* rw1_b  = (const float*)d_in[8];
    const float* rw2_w  = (const float*)d_in[9];
    const float* rw2_b  = (const float*)d_in[10];
    const float* proj_w = (const float*)d_in[11];
    const float* proj_b = (const float*)d_in[12];

    uint8_t* ws = (uint8_t*)d_ws;
    // workspace layout (~157.8 MB):
    __hip_bfloat16* xh  = (__hip_bfloat16*)(ws);                    // 102,760,448 B; later reused as hw
    __hip_bfloat16* xb  = (__hip_bfloat16*)(ws + 102760448);        //  51,380,224 B; later reused as hpre
    uint8_t* wt         = ws + 102760448 + 51380224;                // 154,140,672
    __hip_bfloat16* fcwT  = (__hip_bfloat16*)(wt);                  // 1,048,576 B
    __hip_bfloat16* fc1T  = fcwT + 524288;                          // 1,048,576 B
    __hip_bfloat16* fc2T  = fc1T + 524288;                          // 1,048,576 B
    __hip_bfloat16* projT = fc2T + 524288;                          //   524,288 B
    float* s0 = (float*)(wt + 3670016);                             // 4096 B
    float* s1 = s0 + 1024;                                          // 4096 B
    float* a0 = s1 + 1024;                                          // 4096 B
    float* a1 = a0 + 1024;                                          // 4096 B

    // scratch living inside d_out (dead before final GEMM writes d_out):
    __hip_bfloat16* xs   = (__hip_bfloat16*)d_out;  // [N,1024] bf16 = exactly out bytes
    __hip_bfloat16* wbuf = (__hip_bfloat16*)d_out;  // [N,512]  bf16 (xs dead by then)
    __hip_bfloat16* hpre = xb;                      // [N,512]  bf16 (xb dead by then)
    __hip_bfloat16* hw   = xh;                      // [N,512]  bf16 (xh dead by then)

    hipMemsetAsync(s0, 0, 8192, stream);  // zero s0,s1

    cvt_x<<<25088, 256, 0, stream>>>((const float4*)x, xb, 6422528);
    prep_w<<<7168, 256, 0, stream>>>(fc_w, fc1_w, fc2_w, proj_w, fcwT, fc1T, fc2T, projT);

    // GEMM1: xh = gelu(xb @ fc_w + fc_b)   [50176,1024]
    gemm_bt<1, 1><<<dim3(8, 392), 256, 0, stream>>>(xb, fcwT, fc_b, xh, 1024, 512);
    // forward shift
    shift_fwd<<<896, 256, 0, stream>>>(xh, xs);
    // GEMM2: hpre = gelu(xs @ fc1_w + fc1_b)   [50176,512]
    gemm_bt<1, 1><<<dim3(4, 392), 256, 0, stream>>>(xs, fc1T, fc1_b, hpre, 512, 1024);
    // GEMM3: w = gelu(xh @ fc2_w + fc2_b)   [50176,512]  (into d_out; xs dead)
    gemm_bt<1, 1><<<dim3(4, 392), 256, 0, stream>>>(xh, fc2T, fc2_b, wbuf, 512, 1024);
    // masked channel sums of shift_inv(hpre) and w
    reduce_hw<<<896, 256, 0, stream>>>(hpre, wbuf, s0, s1);
    // tiny MLP + softmax -> a0,a1
    tiny_mlp<<<1, 256, 0, stream>>>(s0, s1, rw1_w, rw1_b, rw2_w, rw2_b, a0, a1);
    // hw = shift_inv(hpre)*a0 + w*a1  (into xh region; xh dead)
    combine<<<896, 256, 0, stream>>>(hpre, wbuf, a0, a1, hw);
    // GEMM4: out = hw @ proj_w + proj_b  fp32 -> d_out (overwrites scratch, all 25.7M written)
    gemm_bt<0, 0><<<dim3(4, 392), 256, 0, stream>>>(hw, projT, proj_b, d_out, 512, 512);
}

// Round 2
// 657.566 us; speedup vs baseline: 1.2086x; 1.2086x over previous
//
#include <hip/hip_runtime.h>
#include <hip/hip_bf16.h>
#include <stdint.h>

// ---------------------------------------------------------------------------
// Mlp_cnn_shift: B=2 T=8 H=56 W=56 C=512 HID=1024, N = 50176 tokens
//  xb   = bf16(x)                                   [N,512]
//  GEMM1: xh = gelu(xb@fc_w+b); dual-store: xh + forward-shift scatter -> xs
//  GEMM2: hs = inverse-shift scatter of gelu(xs@fc1_w+b); fused s0 sum
//  GEMM3: w  = gelu(xh@fc2_w+b); fused s1 sum
//  tiny MLP + pairwise softmax -> a0,a1 (fp32 exact)
//  combine: hw = hs*a0 + w*a1 (shift-free, 16B vectorized)
//  GEMM4: out = hw @ proj_w + proj_b (fp32)
// Shift boundary holes pre-zeroed by zero_holes (3.5% strips).
// ---------------------------------------------------------------------------

typedef __attribute__((ext_vector_type(8))) short short8;
typedef __attribute__((ext_vector_type(4))) float floatx4;
typedef unsigned int uint;
typedef unsigned short ushort;

#define NTOK   50176
#define HWIMG  3136    // 56*56

// exact gelu (tiny MLP only)
__device__ __forceinline__ float gelu_exact(float v) {
    return 0.5f * v * (1.0f + erff(v * 0.70710678118654752440f));
}
// tanh-approx gelu = v * sigmoid(2u), u = 0.79788456*(v + 0.044715 v^3)
// max abs err ~3e-4; used for the 102.8M big-GEMM activations
__device__ __forceinline__ float gelu_fast(float v) {
    float u = v * (0.7978845608f + 0.0356774081f * v * v);
    return v * __builtin_amdgcn_rcpf(1.0f + __expf(-2.0f * u));
}

// shifts: g in 0..8 -> (1-g/3, 1-g%3) matches SHIFTS table
__device__ __forceinline__ int shift_h(int g) { return 1 - g / 3; }
__device__ __forceinline__ int shift_w(int g) { return 1 - g % 3; }

// ---- async global->LDS, 16B per lane ---------------------------------------
typedef const __attribute__((address_space(1))) uint* gas_ptr;
typedef __attribute__((address_space(3))) uint* las_ptr;

__device__ __forceinline__ void async_copy16(const void* g, void* l) {
    gas_ptr gp = (gas_ptr)(uintptr_t)g;
    las_ptr lp = (las_ptr)(uint32_t)(uintptr_t)l;
    __builtin_amdgcn_global_load_lds(gp, lp, 16, 0, 0);
}

// ---- GEMM: C[M,N] = act(A[M,K] @ Bt[N,K]^T + bias) -------------------------
// BM=BN=128, BK=32, 256 thr = 4 waves (2x2), wave 64x64 via 4x4 mfma 16x16x32.
// EPI: 0 = fp32 plain store (GEMM4)
//      1 = gelu bf16 store + forward-shift scatter to Cout2 (GEMM1, N=1024)
//      2 = gelu bf16 inverse-shift scatter ONLY + fused sum -> ssum (GEMM2)
//      3 = gelu bf16 plain store + fused sum -> ssum (GEMM3)
template <int EPI>
__global__ __launch_bounds__(256) void gemm_bt(
    const __hip_bfloat16* __restrict__ A,
    const __hip_bfloat16* __restrict__ Bt,
    const float* __restrict__ bias,
    void* __restrict__ Cout, __hip_bfloat16* __restrict__ Cout2,
    float* __restrict__ ssum, int N, int K)
{
    __shared__ __hip_bfloat16 As[128 * 32];
    __shared__ __hip_bfloat16 Bs[128 * 32];

    const int t    = threadIdx.x;
    const int lane = t & 63;
    const int wave = t >> 6;
    const int wm   = wave >> 1;
    const int wn   = wave & 1;

    // XCD swizzle: round-robin dispatch puts flat%8 on XCD flat&7; give each
    // XCD a contiguous bm range so its private L2 keeps the A-tiles.
    const int nbn  = gridDim.x;                 // 392 = 8*49 assumed for y
    const int flat = blockIdx.y * nbn + blockIdx.x;
    const int xcd  = flat & 7;
    const int j    = flat >> 3;
    const int jd   = j / nbn;
    const int bm   = xcd * 49 + jd;
    const int bn   = j - jd * nbn;

    const __hip_bfloat16* ga0 = A  + (size_t)(bm * 128 + (t >> 2)) * K + (t & 3) * 8;
    const __hip_bfloat16* ga1 = ga0 + (size_t)64 * K;
    const __hip_bfloat16* gb0 = Bt + (size_t)(bn * 128 + (t >> 2)) * K + (t & 3) * 8;
    const __hip_bfloat16* gb1 = gb0 + (size_t)64 * K;
    __hip_bfloat16* la0 = &As[t * 8];
    __hip_bfloat16* la1 = &As[t * 8 + 2048];
    __hip_bfloat16* lb0 = &Bs[t * 8];
    __hip_bfloat16* lb1 = &Bs[t * 8 + 2048];

    floatx4 acc[4][4] = {};

    const int kq = (lane >> 4) * 8;
    const int ml = lane & 15;

    for (int k0 = 0; k0 < K; k0 += 32) {
        async_copy16(ga0, la0);
        async_copy16(ga1, la1);
        async_copy16(gb0, lb0);
        async_copy16(gb1, lb1);
        ga0 += 32; ga1 += 32; gb0 += 32; gb1 += 32;
        asm volatile("s_waitcnt vmcnt(0)" ::: "memory");
        __syncthreads();

        short8 af[4], bf[4];
#pragma unroll
        for (int i = 0; i < 4; i++) {
            af[i] = *(const short8*)&As[(wm * 64 + i * 16 + ml) * 32 + kq];
            bf[i] = *(const short8*)&Bs[(wn * 64 + i * 16 + ml) * 32 + kq];
        }
#pragma unroll
        for (int mi = 0; mi < 4; mi++)
#pragma unroll
            for (int ni = 0; ni < 4; ni++)
                acc[mi][ni] = __builtin_amdgcn_mfma_f32_16x16x32_bf16(
                    af[mi], bf[ni], acc[mi][ni], 0, 0, 0);
        __syncthreads();
    }

    // epilogue: C/D layout col = lane&15, row = (lane>>4)*4 + reg (m89)
    const int rq = (lane >> 4) * 4;

    int cols[4], gsh[4], gsw[4];
    float bv[4];
    float sum[4] = {0.f, 0.f, 0.f, 0.f};
#pragma unroll
    for (int ni = 0; ni < 4; ni++) {
        const int col = bn * 128 + wn * 64 + ni * 16 + ml;
        cols[ni] = col;
        bv[ni] = bias[col];
        if (EPI == 1) { const int g = col / 114; gsh[ni] = shift_h(g); gsw[ni] = shift_w(g); }
        if (EPI == 2) { const int g = col / 57;  gsh[ni] = shift_h(g); gsw[ni] = shift_w(g); }
    }

#pragma unroll
    for (int mi = 0; mi < 4; mi++) {
        const int row0 = bm * 128 + wm * 64 + mi * 16 + rq;
        int phr[4], pwr[4];
        if (EPI == 1 || EPI == 2) {
            const int bt_ = row0 / HWIMG;
            const int rem = row0 - bt_ * HWIMG;
            const int ph0 = rem / 56;
            const int pw0 = rem - ph0 * 56;
#pragma unroll
            for (int r = 0; r < 4; r++) {
                int pw = pw0 + r, ph = ph0;
                if (pw >= 56) { pw -= 56; ph += 1; }
                if (ph >= 56) { ph = 0; }
                phr[r] = ph; pwr[r] = pw;
            }
        }
#pragma unroll
        for (int ni = 0; ni < 4; ni++) {
            const int col = cols[ni];
#pragma unroll
            for (int r = 0; r < 4; r++) {
                const int tok = row0 + r;
                float v = acc[mi][ni][r] + bv[ni];
                if (EPI != 0) v = gelu_fast(v);
                if (EPI == 0) {
                    ((float*)Cout)[(size_t)tok * N + col] = v;
                } else if (EPI == 1) {
                    const __hip_bfloat16 bvv = __float2bfloat16(v);
                    ((__hip_bfloat16*)Cout)[(size_t)tok * N + col] = bvv;
                    const int th = phr[r] + gsh[ni], tw = pwr[r] + gsw[ni];
                    if ((unsigned)th < 56u && (unsigned)tw < 56u)
                        Cout2[(size_t)(tok + gsh[ni] * 56 + gsw[ni]) * N + col] = bvv;
                } else if (EPI == 2) {
                    const int th = phr[r] - gsh[ni], tw = pwr[r] - gsw[ni];
                    if ((unsigned)th < 56u && (unsigned)tw < 56u) {
                        ((__hip_bfloat16*)Cout)[(size_t)(tok - gsh[ni] * 56 - gsw[ni]) * N + col]
                            = __float2bfloat16(v);
                        sum[ni] += v;
                    }
                } else {
                    ((__hip_bfloat16*)Cout)[(size_t)tok * N + col] = __float2bfloat16(v);
                    sum[ni] += v;
                }
            }
        }
    }

    if (EPI == 2 || EPI == 3) {
        const int b = (bm >= 196) ? 1 : 0;   // token 25088 = block 196 boundary
#pragma unroll
        for (int ni = 0; ni < 4; ni++) {
            float s = sum[ni];
            s += __shfl_xor(s, 16, 64);
            s += __shfl_xor(s, 32, 64);
            if (lane < 16) atomicAdd(&ssum[b * 512 + cols[ni]], s);
        }
    }
}

// ---- zero the shift boundary holes (frame strips only, ~3.5%) --------------
// buf[bt,oh,ow,c] is a hole iff source (ih=oh-SGN*sh, iw=ow-SGN*sw) out of range.
// xs: SGN=+1 (xs[o]=xh[o-s]); hs: SGN=-1 (hs[o]=hpre[o+s]).
template <int C, int GS, int SGN>
__global__ __launch_bounds__(256) void zero_holes(__hip_bfloat16* __restrict__ buf)
{
    const int i = blockIdx.x * 256 + threadIdx.x;   // 16*220*C exact
    const int c = i % C;
    const int p = i / C;
    const int bt = p / 220, fp = p % 220;
    int oh, ow;
    if (fp < 56)       { oh = 0;        ow = fp; }
    else if (fp < 112) { oh = 55;       ow = fp - 56; }
    else if (fp < 166) { oh = fp - 111; ow = 0; }
    else               { oh = fp - 165; ow = 55; }
    const int g = c / GS;
    const int ih = oh - SGN * shift_h(g);
    const int iw = ow - SGN * shift_w(g);
    if ((unsigned)ih >= 56u || (unsigned)iw >= 56u)
        buf[((size_t)(bt * HWIMG + oh * 56 + ow)) * C + c] = __float2bfloat16(0.0f);
}

// ---- prep: x fp32 -> bf16 ---------------------------------------------------
__global__ __launch_bounds__(256) void cvt_x(const float4* __restrict__ x,
                                             __hip_bfloat16* __restrict__ xb)
{
    int i = blockIdx.x * 256 + threadIdx.x;
    float4 v = x[i];
    __hip_bfloat16 b0 = __float2bfloat16(v.x);
    __hip_bfloat16 b1 = __float2bfloat16(v.y);
    __hip_bfloat16 b2 = __float2bfloat16(v.z);
    __hip_bfloat16 b3 = __float2bfloat16(v.w);
    uint2 o;
    o.x = (uint)*(ushort*)&b0 | ((uint)*(ushort*)&b1 << 16);
    o.y = (uint)*(ushort*)&b2 | ((uint)*(ushort*)&b3 << 16);
    *(uint2*)&xb[(size_t)i * 4] = o;
}

// ---- prep: transpose + convert the 4 weight matrices to bf16 Bt layout -----
__global__ __launch_bounds__(256) void prep_w(
    const float* __restrict__ fcw,  const float* __restrict__ fc1w,
    const float* __restrict__ fc2w, const float* __restrict__ projw,
    __hip_bfloat16* __restrict__ fcwT, __hip_bfloat16* __restrict__ fc1T,
    __hip_bfloat16* __restrict__ fc2T, __hip_bfloat16* __restrict__ projT)
{
    int i = blockIdx.x * 256 + threadIdx.x;
    if (i < 524288) {                       // fc_w [512,1024] -> [1024,512]
        int n = i >> 9, k = i & 511;
        fcwT[i] = __float2bfloat16(fcw[k * 1024 + n]);
    } else if (i < 1048576) {               // fc1_w [1024,512] -> [512,1024]
        int j = i - 524288;
        int n = j >> 10, k = j & 1023;
        fc1T[j] = __float2bfloat16(fc1w[k * 512 + n]);
    } else if (i < 1572864) {               // fc2_w [1024,512] -> [512,1024]
        int j = i - 1048576;
        int n = j >> 10, k = j & 1023;
        fc2T[j] = __float2bfloat16(fc2w[k * 512 + n]);
    } else if (i < 1835008) {               // proj_w [512,512] -> [512,512]
        int j = i - 1572864;
        int n = j >> 9, k = j & 511;
        projT[j] = __float2bfloat16(projw[k * 512 + n]);
    }
}

// ---- tiny squeeze-excite MLP + pairwise softmax, fp32 exact ----------------
__global__ __launch_bounds__(256) void tiny_mlp(
    const float* __restrict__ s0, const float* __restrict__ s1,
    const float* __restrict__ rw1_w, const float* __restrict__ rw1_b,
    const float* __restrict__ rw2_w, const float* __restrict__ rw2_b,
    float* __restrict__ a0, float* __restrict__ a1)
{
    __shared__ float mean[1024];   // [2][512]
    __shared__ float z[256];       // [2][128]
    __shared__ float av[2048];     // [2][1024]
    const int t = threadIdx.x;
    for (int i = t; i < 1024; i += 256)
        mean[i] = (s0[i] + s1[i]) * (1.0f / 25088.0f);
    __syncthreads();
    {
        const int b = t >> 7, j = t & 127;
        float acc = rw1_b[j];
        for (int cc = 0; cc < 512; cc++)
            acc += mean[b * 512 + cc] * rw1_w[cc * 128 + j];
        z[t] = gelu_exact(acc);
    }
    __syncthreads();
    for (int i = t; i < 2048; i += 256) {
        const int b = i >> 10, o = i & 1023;
        float acc = rw2_b[o];
        for (int j = 0; j < 128; j++)
            acc += z[b * 128 + j] * rw2_w[j * 1024 + o];
        av[i] = acc;
    }
    __syncthreads();
    for (int i = t; i < 1024; i += 256) {
        const int b = i >> 9, cc = i & 511;
        const float x0 = av[b * 1024 + 2 * cc];
        const float x1 = av[b * 1024 + 2 * cc + 1];
        const float m = fmaxf(x0, x1);
        const float e0 = expf(x0 - m), e1 = expf(x1 - m);
        const float inv = 1.0f / (e0 + e1);
        a0[i] = e0 * inv;
        a1[i] = e1 * inv;
    }
}

// ---- hw = hs*a0 + w*a1 (shift-free, 8 channels / thread) --------------------
__device__ __forceinline__ float bf_lo(uint u) { return __uint_as_float(u << 16); }
__device__ __forceinline__ float bf_hi(uint u) { return __uint_as_float(u & 0xffff0000u); }
__device__ __forceinline__ uint pack_bf2(float lo, float hi) {
    __hip_bfloat16 a = __float2bfloat16(lo), b = __float2bfloat16(hi);
    return (uint)*(ushort*)&a | ((uint)*(ushort*)&b << 16);
}

__global__ __launch_bounds__(256) void combine(
    const uint4* __restrict__ hs4, const uint4* __restrict__ w4,
    const float* __restrict__ a0, const float* __restrict__ a1,
    uint4* __restrict__ hw4)
{
    const int i = blockIdx.x * 256 + threadIdx.x;   // 3,211,264 exact
    const int ck = i & 63;                          // 8-channel chunk
    const int tok = i >> 6;
    const int b = (tok >= 25088) ? 1 : 0;
    const float4* A0 = (const float4*)&a0[b * 512 + ck * 8];
    const float4* A1 = (const float4*)&a1[b * 512 + ck * 8];
    const float4 s0l = A0[0], s0h = A0[1];
    const float4 s1l = A1[0], s1h = A1[1];
    const uint4 h = hs4[i], w = w4[i];
    uint4 o;
    o.x = pack_bf2(bf_lo(h.x) * s0l.x + bf_lo(w.x) * s1l.x,
                   bf_hi(h.x) * s0l.y + bf_hi(w.x) * s1l.y);
    o.y = pack_bf2(bf_lo(h.y) * s0l.z + bf_lo(w.y) * s1l.z,
                   bf_hi(h.y) * s0l.w + bf_hi(w.y) * s1l.w);
    o.z = pack_bf2(bf_lo(h.z) * s0h.x + bf_lo(w.z) * s1h.x,
                   bf_hi(h.z) * s0h.y + bf_hi(w.z) * s1h.y);
    o.w = pack_bf2(bf_lo(h.w) * s0h.z + bf_lo(w.w) * s1h.z,
                   bf_hi(h.w) * s0h.w + bf_hi(w.w) * s1h.w);
    hw4[i] = o;
}

// ---------------------------------------------------------------------------
extern "C" void kernel_launch(void* const* d_in, const int* in_sizes, int n_in,
                              void* d_out, int out_size, void* d_ws, size_t ws_size,
                              hipStream_t stream)
{
    const float* x      = (const float*)d_in[0];
    const float* fc_w   = (const float*)d_in[1];
    const float* fc_b   = (const float*)d_in[2];
    const float* fc1_w  = (const float*)d_in[3];
    const float* fc1_b  = (const float*)d_in[4];
    const float* fc2_w  = (const float*)d_in[5];
    const float* fc2_b  = (const float*)d_in[6];
    const float* rw1_w  = (const float*)d_in[7];
    const float* rw1_b  = (const float*)d_in[8];
    const float* rw2_w  = (const float*)d_in[9];
    const float* rw2_b  = (const float*)d_in[10];
    const float* proj_w = (const float*)d_in[11];
    const float* proj_b = (const float*)d_in[12];

    uint8_t* ws = (uint8_t*)d_ws;
    __hip_bfloat16* xh  = (__hip_bfloat16*)(ws);                    // [N,1024] bf16, later hw
    __hip_bfloat16* xb  = (__hip_bfloat16*)(ws + 102760448);        // [N,512] bf16, later hs
    uint8_t* wt         = ws + 102760448 + 51380224;
    __hip_bfloat16* fcwT  = (__hip_bfloat16*)(wt);
    __hip_bfloat16* fc1T  = fcwT + 524288;
    __hip_bfloat16* fc2T  = fc1T + 524288;
    __hip_bfloat16* projT = fc2T + 524288;
    float* s0 = (float*)(wt + 3670016);
    float* s1 = s0 + 1024;
    float* a0 = s1 + 1024;
    float* a1 = a0 + 1024;

    __hip_bfloat16* xs   = (__hip_bfloat16*)d_out;  // [N,1024] bf16 (dead after GEMM2)
    __hip_bfloat16* wbuf = (__hip_bfloat16*)d_out;  // [N,512]  bf16 (dead after combine)
    __hip_bfloat16* hs   = xb;                      // [N,512]  bf16 (xb dead after GEMM1)
    __hip_bfloat16* hw   = xh;                      // [N,512]  bf16 (xh dead after GEMM3)

    hipMemsetAsync(s0, 0, 8192, stream);            // zero s0,s1

    // xs boundary holes (d_out, no deps) — before GEMM1's scatter fills valid cells
    zero_holes<1024, 114, +1><<<14080, 256, 0, stream>>>(xs);
    cvt_x<<<25088, 256, 0, stream>>>((const float4*)x, xb);
    prep_w<<<7168, 256, 0, stream>>>(fc_w, fc1_w, fc2_w, proj_w, fcwT, fc1T, fc2T, projT);

    // GEMM1: xh = gelu(xb@fc_w+b); dual store xh + fwd-shift scatter -> xs
    gemm_bt<1><<<dim3(8, 392), 256, 0, stream>>>(xb, fcwT, fc_b, xh, xs, nullptr, 1024, 512);
    // hs boundary holes (hs aliases xb -> must run after GEMM1)
    zero_holes<512, 57, -1><<<7040, 256, 0, stream>>>(hs);
    // GEMM2: hs = inv-shift scatter of gelu(xs@fc1_w+b); fused s0
    gemm_bt<2><<<dim3(4, 392), 256, 0, stream>>>(xs, fc1T, fc1_b, hs, nullptr, s0, 512, 1024);
    // GEMM3: w = gelu(xh@fc2_w+b) -> d_out (xs dead); fused s1
    gemm_bt<3><<<dim3(4, 392), 256, 0, stream>>>(xh, fc2T, fc2_b, wbuf, nullptr, s1, 512, 1024);
    // tiny MLP + softmax -> a0,a1
    tiny_mlp<<<1, 256, 0, stream>>>(s0, s1, rw1_w, rw1_b, rw2_w, rw2_b, a0, a1);
    // hw = hs*a0 + w*a1 -> xh region
    combine<<<12544, 256, 0, stream>>>((const uint4*)hs, (const uint4*)wbuf, a0, a1, (uint4*)hw);
    // GEMM4: out = hw @ proj_w + proj_b, fp32 -> d_out
    gemm_bt<0><<<dim3(4, 392), 256, 0, stream>>>(hw, projT, proj_b, d_out, nullptr, nullptr, 512, 512);
}